// Round 3
// baseline (70.639 us; speedup 1.0000x reference)
//
#include <hip/hip_runtime.h>
#include <hip/hip_bf16.h>

#define EPSF 1e-5f

namespace {
constexpr int B = 64, D = 20000, C = 16, H = 64, EH = 128, L = 32;
constexpr int CHUNK = 256;                      // points per block
constexpr int NCHUNK = (D + CHUNK - 1) / CHUNK; // 79
}

typedef __attribute__((ext_vector_type(8))) short bf16x8;
typedef __attribute__((ext_vector_type(4))) float f32x4;

static __device__ __forceinline__ unsigned short f2bf(float f) {
    __hip_bfloat16 h = __float2bfloat16(f);
    return __builtin_bit_cast(unsigned short, h);
}
static __device__ __forceinline__ unsigned int packbf(float lo, float hi) {
    return ((unsigned int)f2bf(hi) << 16) | (unsigned int)f2bf(lo);
}

// ---------- Phase A: per-(batch,chunk) observed-count ----------
__global__ __launch_bounds__(256) void k_count(
    const int* __restrict__ mask, int* __restrict__ chunkpop)
{
    const int b = blockIdx.y, j = blockIdx.x;
    const int d = j * CHUNK + threadIdx.x;
    const int mv = (d < D) ? mask[(size_t)b * D + d] : 0;
    const unsigned long long bal = __ballot(mv != 0);
    __shared__ int ws[4];
    const int lane = threadIdx.x & 63, wid = threadIdx.x >> 6;
    if (lane == 0) ws[wid] = __popcll(bal);
    __syncthreads();
    if (threadIdx.x == 0)
        chunkpop[b * NCHUNK + j] = ws[0] + ws[1] + ws[2] + ws[3];
}

// ---------- Phase B: per-batch exclusive scan of chunk counts ----------
__global__ __launch_bounds__(128) void k_scan(
    const int* __restrict__ chunkpop, int* __restrict__ chunkoff,
    int* __restrict__ cnt)
{
    const int b = blockIdx.x;
    const int t = threadIdx.x;
    __shared__ int sbuf[128];
    const int v = (t < NCHUNK) ? chunkpop[b * NCHUNK + t] : 0;
    sbuf[t] = v;
    __syncthreads();
    #pragma unroll
    for (int off = 1; off < 128; off <<= 1) {
        int add = (t >= off) ? sbuf[t - off] : 0;
        __syncthreads();
        sbuf[t] += add;
        __syncthreads();
    }
    if (t < NCHUNK) chunkoff[b * NCHUNK + t] = sbuf[t] - v;  // exclusive
    if (t == 0) cnt[b] = sbuf[NCHUNK - 1];
}

// ---------- Phase C: scatter observed d-indices (deterministic order) ----------
__global__ __launch_bounds__(256) void k_scatter(
    const int* __restrict__ mask, const int* __restrict__ chunkoff,
    unsigned short* __restrict__ cd)
{
    const int b = blockIdx.y, j = blockIdx.x;
    const int d = j * CHUNK + threadIdx.x;
    const int mv = (d < D) ? mask[(size_t)b * D + d] : 0;
    const unsigned long long bal = __ballot(mv != 0);
    const int lane = threadIdx.x & 63, wid = threadIdx.x >> 6;
    __shared__ int ws[4];
    if (lane == 0) ws[wid] = __popcll(bal);
    __syncthreads();
    int woff = 0;
    for (int w = 0; w < wid; ++w) woff += ws[w];
    const int pre = __popcll(bal & ((1ull << lane) - 1ull));
    if (mv)
        cd[(size_t)b * D + chunkoff[b * NCHUNK + j] + woff + pre] =
            (unsigned short)d;
}

// ---------- Main pointnet via MFMA over compacted entries ----------
// One wave processes 16 points per MFMA group; 4 groups per wave; 4 waves/block
// -> 256 points per block (CHUNK).
// Layer 1 (flipped): t1^T[h][r] = W1^T(A) @ hin^T(B), 4 M-tiles of 16 h.
// Layer 2 (flipped): a2^T[c][r] = W2^T(A) @ r^T(B),   K=64 in 2 steps.
__global__ __launch_bounds__(256) void k_rows(
    const float* __restrict__ x, const unsigned short* __restrict__ cd,
    const int* __restrict__ cnt, const float* __restrict__ fe,
    const float* __restrict__ W1, const float* __restrict__ b1,
    const float* __restrict__ g1, const float* __restrict__ be1,
    const float* __restrict__ W2, const float* __restrict__ b2,
    const float* __restrict__ g2, const float* __restrict__ be2,
    float* __restrict__ part)    // [B][NCHUNK][C]
{
    const int b = blockIdx.y;
    const int chunk = blockIdx.x;
    const int cbase = chunk * CHUNK;
    const int n = cnt[b];
    if (cbase >= n) return;

    const int tid  = threadIdx.x;
    const int w    = tid >> 6;       // wave id 0..3
    const int lane = tid & 63;
    const int g    = lane >> 4;      // lane group 0..3
    const int q    = lane & 15;      // column / point-row / h-row index

    // Per-wave LDS. A1s: hin^T staging [16 pts][32 k] bf16 (k: 0..15=fe,16=x,
    // 17..31=0). Rs: relu(LN(t1)) [16 pts][72 (64 used, 8 pad)] bf16.
    __shared__ __align__(16) unsigned short A1s[4][16][32];
    __shared__ __align__(16) unsigned short Rs[4][16][72];
    __shared__ float wsum[4][16];

    // ---- one-time per-wave setup: weight fragments in registers ----
    // W1^T A-frags: tile m rows h=16m+q, k-elem j -> logical col kk=8g+j.
    // kk<16 -> W1 row kk+1 (fe part); kk==16 -> W1 row 0 (x); else 0.
    bf16x8 w1f[4];
    #pragma unroll
    for (int m = 0; m < 4; ++m) {
        #pragma unroll
        for (int j = 0; j < 8; ++j) {
            const int kk = 8 * g + j;
            const int wr = (kk < 16) ? (kk + 1) : ((kk == 16) ? 0 : -1);
            const float v = (wr >= 0) ? W1[wr * H + 16 * m + q] : 0.f;
            w1f[m][j] = (short)f2bf(v);
        }
    }
    // W2^T A-frags: rows c=q, k = h = 8g+j+32ks.
    bf16x8 w2f[2];
    #pragma unroll
    for (int ks = 0; ks < 2; ++ks) {
        #pragma unroll
        for (int j = 0; j < 8; ++j) {
            const int h = 8 * g + j + 32 * ks;
            w2f[ks][j] = (short)f2bf(W2[h * C + q]);
        }
    }
    // per-lane LN affine params: layer1 h = 16m+4g+reg; layer2 c = 4g+reg.
    float4 g1v[4], be1v[4];
    #pragma unroll
    for (int m = 0; m < 4; ++m) {
        g1v[m]  = *(const float4*)(g1  + 16 * m + 4 * g);
        be1v[m] = *(const float4*)(be1 + 16 * m + 4 * g);
    }
    const float4 b1v  = *(const float4*)(b1 + 16 * 0 + 4 * g); // b1 is 0 in ref but keep exact
    float4 b1vm[4];
    #pragma unroll
    for (int m = 0; m < 4; ++m) b1vm[m] = *(const float4*)(b1 + 16 * m + 4 * g);
    (void)b1v;
    const float4 g2v  = *(const float4*)(g2  + 4 * g);
    const float4 be2v = *(const float4*)(be2 + 4 * g);
    const float4 b2v  = *(const float4*)(b2  + 4 * g);

    // zero A1s cols 16..31 once (col 16 overwritten by x each group)
    {
        const int r16 = lane >> 2, sub = lane & 3;
        *(uint2*)&A1s[w][r16][16 + sub * 4] = make_uint2(0u, 0u);
    }

    float acc[4] = {0.f, 0.f, 0.f, 0.f};   // pool partials, c = 4g+reg

    #pragma unroll
    for (int it = 0; it < 4; ++it) {
        const int gbase = cbase + (w * 4 + it) * 16;
        if (gbase >= n) continue;           // wave-uniform

        // ---- stage hin^T into A1s (bf16) ----
        {
            const int r16 = lane >> 2, sub = lane & 3;
            const int irow = gbase + r16;
            const bool vr = irow < n;
            const int d = vr ? (int)cd[(size_t)b * D + irow] : 0;
            float4 fv = make_float4(0.f, 0.f, 0.f, 0.f);
            if (vr) fv = *(const float4*)(fe + (size_t)d * C + sub * 4);
            uint2 pk = make_uint2(packbf(fv.x, fv.y), packbf(fv.z, fv.w));
            *(uint2*)&A1s[w][r16][sub * 4] = pk;
        }
        {
            const int irow = gbase + q;
            const bool vr = irow < n;
            float xv = 0.f;
            if (vr && g == 0) {
                const int d = (int)cd[(size_t)b * D + irow];
                xv = x[(size_t)b * D + d];
            }
            if (g == 0) A1s[w][q][16] = f2bf(xv);
        }

        // ---- layer 1 MFMA: B-frag = hin^T (col=q, k=8g+j) ----
        const bf16x8 hb = *(const bf16x8*)&A1s[w][q][g * 8];
        f32x4 t1a[4];
        #pragma unroll
        for (int m = 0; m < 4; ++m) {
            f32x4 z = {0.f, 0.f, 0.f, 0.f};
            t1a[m] = __builtin_amdgcn_mfma_f32_16x16x32_bf16(w1f[m], hb, z, 0, 0, 0);
            // + b1 (h = 16m+4g+reg)
            t1a[m][0] += b1vm[m].x; t1a[m][1] += b1vm[m].y;
            t1a[m][2] += b1vm[m].z; t1a[m][3] += b1vm[m].w;
        }

        // ---- LN over h=64 for point r=q (reduce across lane groups) ----
        float s = 0.f, sq = 0.f;
        #pragma unroll
        for (int m = 0; m < 4; ++m) {
            #pragma unroll
            for (int r = 0; r < 4; ++r) {
                const float v = t1a[m][r];
                s += v; sq = fmaf(v, v, sq);
            }
        }
        s  += __shfl_xor(s, 16);  sq += __shfl_xor(sq, 16);
        s  += __shfl_xor(s, 32);  sq += __shfl_xor(sq, 32);
        const float mean1 = s * (1.f / H);
        const float var1  = fmaxf(sq * (1.f / H) - mean1 * mean1, 0.f);
        const float rstd1 = rsqrtf(var1 + EPSF);

        // normalize+affine+relu -> bf16 -> Rs[point q][h]
        #pragma unroll
        for (int m = 0; m < 4; ++m) {
            float v0 = fmaxf(fmaf((t1a[m][0] - mean1) * rstd1, g1v[m].x, be1v[m].x), 0.f);
            float v1 = fmaxf(fmaf((t1a[m][1] - mean1) * rstd1, g1v[m].y, be1v[m].y), 0.f);
            float v2 = fmaxf(fmaf((t1a[m][2] - mean1) * rstd1, g1v[m].z, be1v[m].z), 0.f);
            float v3 = fmaxf(fmaf((t1a[m][3] - mean1) * rstd1, g1v[m].w, be1v[m].w), 0.f);
            uint2 pk = make_uint2(packbf(v0, v1), packbf(v2, v3));
            *(uint2*)&Rs[w][q][16 * m + 4 * g] = pk;   // h0 = 16m+4g
        }

        // ---- layer 2 MFMA: B-frag = r^T (col=q, k=h=8g+j+32ks) ----
        const bf16x8 rb0 = *(const bf16x8*)&Rs[w][q][g * 8];
        const bf16x8 rb1 = *(const bf16x8*)&Rs[w][q][32 + g * 8];
        f32x4 a2;
        {
            f32x4 z = {0.f, 0.f, 0.f, 0.f};
            a2 = __builtin_amdgcn_mfma_f32_16x16x32_bf16(w2f[0], rb0, z, 0, 0, 0);
            a2 = __builtin_amdgcn_mfma_f32_16x16x32_bf16(w2f[1], rb1, a2, 0, 0, 0);
        }
        a2[0] += b2v.x; a2[1] += b2v.y; a2[2] += b2v.z; a2[3] += b2v.w;

        // ---- LN over c=16 for point r=q ----
        float s2 = (a2[0] + a2[1]) + (a2[2] + a2[3]);
        float q2 = fmaf(a2[0], a2[0], fmaf(a2[1], a2[1],
                   fmaf(a2[2], a2[2], a2[3] * a2[3])));
        s2 += __shfl_xor(s2, 16);  q2 += __shfl_xor(q2, 16);
        s2 += __shfl_xor(s2, 32);  q2 += __shfl_xor(q2, 32);
        const float mean2 = s2 * (1.f / C);
        const float var2  = fmaxf(q2 * (1.f / C) - mean2 * mean2, 0.f);
        const float rstd2 = rsqrtf(var2 + EPSF);

        const float vm = (gbase + q < n) ? 1.f : 0.f;
        acc[0] += fmaxf(fmaf((a2[0] - mean2) * rstd2, g2v.x, be2v.x), 0.f) * vm;
        acc[1] += fmaxf(fmaf((a2[1] - mean2) * rstd2, g2v.y, be2v.y), 0.f) * vm;
        acc[2] += fmaxf(fmaf((a2[2] - mean2) * rstd2, g2v.z, be2v.z), 0.f) * vm;
        acc[3] += fmaxf(fmaf((a2[3] - mean2) * rstd2, g2v.w, be2v.w), 0.f) * vm;
    }

    // ---- pool: reduce over the 16 point-columns (lanes sharing g) ----
    #pragma unroll
    for (int off = 1; off < 16; off <<= 1) {
        #pragma unroll
        for (int r = 0; r < 4; ++r)
            acc[r] += __shfl_xor(acc[r], off);
    }
    if (q == 0)
        *(float4*)&wsum[w][4 * g] = make_float4(acc[0], acc[1], acc[2], acc[3]);
    __syncthreads();
    if (tid < C) {
        float v = wsum[0][tid] + wsum[1][tid] + wsum[2][tid] + wsum[3][tid];
        part[((size_t)b * NCHUNK + chunk) * C + tid] = v;
    }
}

// ---------- Encoder MLP per batch ----------
__global__ __launch_bounds__(EH) void k_enc(
    const float* __restrict__ part, const int* __restrict__ cnt,
    const float* __restrict__ We1, const float* __restrict__ bb1,
    const float* __restrict__ gg1, const float* __restrict__ bbe1,
    const float* __restrict__ We2, const float* __restrict__ bb2,
    const float* __restrict__ gg2, const float* __restrict__ bbe2,
    float* __restrict__ out)
{
    const int b = blockIdx.x;
    const int t = threadIdx.x;
    __shared__ float cc[C];
    __shared__ float stats[2];
    __shared__ float buf[EH];
    __shared__ float buf2[2 * L];

    const int n = cnt[b];
    const int nch = (n + CHUNK - 1) / CHUNK;
    if (t < C) {
        float s = 0.f;
        for (int j = 0; j < nch; ++j)
            s += part[((size_t)b * NCHUNK + j) * C + t];
        cc[t] = s;
    }
    __syncthreads();
    const float inv = 1.f / fmaxf((float)n, 1.f);

    float v1 = bb1[t];
    #pragma unroll
    for (int c = 0; c < C; ++c)
        v1 = fmaf(cc[c] * inv, We1[c * EH + t], v1);
    buf[t] = v1;
    __syncthreads();
    if (t == 0) {
        float s = 0.f, ss = 0.f;
        for (int j = 0; j < EH; ++j) { s += buf[j]; ss = fmaf(buf[j], buf[j], ss); }
        float mn = s * (1.f / EH);
        float vr = fmaxf(ss * (1.f / EH) - mn * mn, 0.f);
        stats[0] = mn; stats[1] = rsqrtf(vr + EPSF);
    }
    __syncthreads();
    float e1 = fmaxf(fmaf((v1 - stats[0]) * stats[1], gg1[t], bbe1[t]), 0.f);
    __syncthreads();
    buf[t] = e1;
    __syncthreads();

    float v2 = 0.f;
    if (t < 2 * L) {
        v2 = bb2[t];
        #pragma unroll
        for (int h = 0; h < EH; ++h)
            v2 = fmaf(buf[h], We2[h * (2 * L) + t], v2);
        buf2[t] = v2;
    }
    __syncthreads();
    if (t == 0) {
        float s = 0.f, ss = 0.f;
        for (int j = 0; j < 2 * L; ++j) { s += buf2[j]; ss = fmaf(buf2[j], buf2[j], ss); }
        float mn = s * (1.f / (2 * L));
        float vr = fmaxf(ss * (1.f / (2 * L)) - mn * mn, 0.f);
        stats[0] = mn; stats[1] = rsqrtf(vr + EPSF);
    }
    __syncthreads();
    if (t < 2 * L) {
        float e2 = fmaxf(fmaf((v2 - stats[0]) * stats[1], gg2[t], bbe2[t]), 0.f);
        if (t < L) out[(size_t)b * L + t]                       = e2;  // mu
        else       out[(size_t)B * L + (size_t)b * L + (t - L)] = e2;  // logvar
    }
}

extern "C" void kernel_launch(void* const* d_in, const int* in_sizes, int n_in,
                              void* d_out, int out_size, void* d_ws, size_t ws_size,
                              hipStream_t stream) {
    const float* x    = (const float*)d_in[0];
    const int*   mask = (const int*)d_in[1];
    const float* fe   = (const float*)d_in[2];
    const float* W1   = (const float*)d_in[3];
    const float* b1   = (const float*)d_in[4];
    const float* g1   = (const float*)d_in[5];
    const float* be1  = (const float*)d_in[6];
    const float* W2   = (const float*)d_in[7];
    const float* b2   = (const float*)d_in[8];
    const float* g2   = (const float*)d_in[9];
    const float* be2  = (const float*)d_in[10];
    const float* We1  = (const float*)d_in[11];
    const float* bb1  = (const float*)d_in[12];
    const float* gg1  = (const float*)d_in[13];
    const float* bbe1 = (const float*)d_in[14];
    const float* We2  = (const float*)d_in[15];
    const float* bb2  = (const float*)d_in[16];
    const float* gg2  = (const float*)d_in[17];
    const float* bbe2 = (const float*)d_in[18];
    float* out = (float*)d_out;

    char* wp = (char*)d_ws;
    float* part     = (float*)wp;                    wp += (size_t)B * NCHUNK * C * 4;
    int*   cnt      = (int*)wp;                      wp += (size_t)B * 4;
    int*   chunkpop = (int*)wp;                      wp += (size_t)B * NCHUNK * 4;
    int*   chunkoff = (int*)wp;                      wp += (size_t)B * NCHUNK * 4;
    unsigned short* cd = (unsigned short*)wp;        // B*D ushort

    dim3 gridBD(NCHUNK, B);
    hipLaunchKernelGGL(k_count,   gridBD, dim3(CHUNK), 0, stream, mask, chunkpop);
    hipLaunchKernelGGL(k_scan,    dim3(B), dim3(128),  0, stream, chunkpop, chunkoff, cnt);
    hipLaunchKernelGGL(k_scatter, gridBD, dim3(CHUNK), 0, stream, mask, chunkoff, cd);
    hipLaunchKernelGGL(k_rows,    gridBD, dim3(CHUNK), 0, stream,
                       x, cd, cnt, fe, W1, b1, g1, be1, W2, b2, g2, be2, part);
    hipLaunchKernelGGL(k_enc,     dim3(B), dim3(EH),   0, stream,
                       part, cnt, We1, bb1, gg1, bbe1, We2, bb2, gg2, bbe2, out);
}

// Round 4
// 51.014 us; speedup vs baseline: 1.3847x; 1.3847x over previous
//
#include <hip/hip_runtime.h>
#include <hip/hip_bf16.h>

#define EPSF 1e-5f

namespace {
constexpr int B = 64, D = 20000, C = 16, H = 64, EH = 128, L = 32;
constexpr int CHUNK = 256;
constexpr int NCHUNK = (D + CHUNK - 1) / CHUNK; // 79
constexpr int GX = 12;                          // k_rows blocks per batch
}

typedef __attribute__((ext_vector_type(8))) short bf16x8;
typedef __attribute__((ext_vector_type(4))) float f32x4;

static __device__ __forceinline__ unsigned short f2bf(float f) {
    __hip_bfloat16 h = __float2bfloat16(f);
    return __builtin_bit_cast(unsigned short, h);
}
static __device__ __forceinline__ unsigned int packbf(float lo, float hi) {
    return ((unsigned int)f2bf(hi) << 16) | (unsigned int)f2bf(lo);
}

// ---------- K1: per-(b,chunk) mask popcount + weight/fe prep (fused) ----------
__global__ __launch_bounds__(256) void k_count_prep(
    const int* __restrict__ mask, const float* __restrict__ fe,
    const float* __restrict__ W1, const float* __restrict__ b1,
    const float* __restrict__ W2,
    int* __restrict__ chunkpop, unsigned short* __restrict__ febf,
    unsigned short* __restrict__ W1T, unsigned short* __restrict__ W2T)
{
    const int j = blockIdx.x, b = blockIdx.y;
    const int t = threadIdx.x;
    if (j < NCHUNK) {
        const int d = j * CHUNK + t;
        const int mv = (d < D) ? mask[(size_t)b * D + d] : 0;
        const unsigned long long bal = __ballot(mv != 0);
        __shared__ int ws[4];
        const int lane = t & 63, wid = t >> 6;
        if (lane == 0) ws[wid] = __popcll(bal);
        __syncthreads();
        if (t == 0) chunkpop[b * NCHUNK + j] = ws[0] + ws[1] + ws[2] + ws[3];
    } else {
        // prep duty: 64 blocks (one per b) convert fe -> bf16; b==0/1 do W1T/W2T
        const int gtid = b * 256 + t;
        for (int u = gtid; u < (D * C) / 8; u += B * 256) {
            const float4 f0 = *(const float4*)(fe + (size_t)u * 8);
            const float4 f1 = *(const float4*)(fe + (size_t)u * 8 + 4);
            uint4 pk;
            pk.x = packbf(f0.x, f0.y); pk.y = packbf(f0.z, f0.w);
            pk.z = packbf(f1.x, f1.y); pk.w = packbf(f1.z, f1.w);
            *(uint4*)(febf + (size_t)u * 8) = pk;
        }
        if (b == 0) {
            // W1T[h][kk]: kk<16 -> W1[kk+1][h]; 16 -> W1[0][h] (x); 17 -> b1[h]; else 0
            for (int e = t; e < H * 32; e += 256) {
                const int h = e >> 5, kk = e & 31;
                float v = 0.f;
                if (kk < 16)       v = W1[(kk + 1) * H + h];
                else if (kk == 16) v = W1[h];
                else if (kk == 17) v = b1[h];
                W1T[e] = f2bf(v);
            }
        } else if (b == 1) {
            // W2T[c][h] = W2[h][c]
            for (int e = t; e < C * H; e += 256) {
                const int c = e >> 6, hh = e & 63;
                W2T[e] = f2bf(W2[hh * C + c]);
            }
        }
    }
}

// ---------- K2: scatter with per-block inline prefix scan ----------
__global__ __launch_bounds__(256) void k_scatter(
    const int* __restrict__ mask, const int* __restrict__ chunkpop,
    unsigned short* __restrict__ cd, int* __restrict__ cnt)
{
    const int b = blockIdx.y, j = blockIdx.x;
    const int t = threadIdx.x;
    const int lane = t & 63, wid = t >> 6;

    int val = (t < NCHUNK) ? chunkpop[b * NCHUNK + t] : 0;
    int pre = (t < j) ? val : 0;
    #pragma unroll
    for (int off = 32; off > 0; off >>= 1) {
        val += __shfl_xor(val, off);
        pre += __shfl_xor(pre, off);
    }
    __shared__ int redv[4], redp[4], wc[4];
    if (lane == 0) { redv[wid] = val; redp[wid] = pre; }
    __syncthreads();
    const int total = redv[0] + redv[1] + redv[2] + redv[3];
    const int off0  = redp[0] + redp[1] + redp[2] + redp[3];
    if (j == 0 && t == 0) cnt[b] = total;

    const int d = j * CHUNK + t;
    const int mv = (d < D) ? mask[(size_t)b * D + d] : 0;
    const unsigned long long bal = __ballot(mv != 0);
    if (lane == 0) wc[wid] = __popcll(bal);
    __syncthreads();
    int woff = 0;
    for (int w2 = 0; w2 < wid; ++w2) woff += wc[w2];
    const int prel = __popcll(bal & ((1ull << lane) - 1ull));
    if (mv)
        cd[(size_t)b * D + off0 + woff + prel] = (unsigned short)d;
}

// ---------- K3: persistent MFMA pointnet over compacted entries ----------
// grid (GX, B), 4 waves/block. Per chunk: batch-fetch 4 groups of 16 points
// straight to registers (febf L2-hit), then 4 compute iterations.
// Layer1: t1^T = W1T(A) @ hin^T(B), bias folded in col k=17.
// Layer2: a2^T = W2T(A) @ relu(LN(t1))^T(B) via conflict-free Rs LDS.
__global__ __launch_bounds__(256) void k_rows(
    const float* __restrict__ x, const unsigned short* __restrict__ cd,
    const int* __restrict__ cnt, const unsigned short* __restrict__ febf,
    const unsigned short* __restrict__ W1T, const unsigned short* __restrict__ W2T,
    const float* __restrict__ g1, const float* __restrict__ be1,
    const float* __restrict__ g2, const float* __restrict__ be2,
    const float* __restrict__ b2,
    float* __restrict__ part)      // [B][GX][C]
{
    const int b  = blockIdx.y;
    const int bx = blockIdx.x;
    const int n  = cnt[b];
    const int tid = threadIdx.x;
    const int w = tid >> 6, lane = tid & 63;
    const int g = lane >> 4, q = lane & 15;
    const size_t bD = (size_t)b * D;

    // weight fragments (A-operands), 16B contiguous loads
    bf16x8 w1f[4];
    #pragma unroll
    for (int m = 0; m < 4; ++m)
        w1f[m] = *(const bf16x8*)(W1T + (16 * m + q) * 32 + 8 * g);
    bf16x8 w2f[2];
    #pragma unroll
    for (int ks = 0; ks < 2; ++ks)
        w2f[ks] = *(const bf16x8*)(W2T + q * 64 + 32 * ks + 8 * g);

    float4 g1v[4], be1v[4];
    #pragma unroll
    for (int m = 0; m < 4; ++m) {
        g1v[m]  = *(const float4*)(g1  + 16 * m + 4 * g);
        be1v[m] = *(const float4*)(be1 + 16 * m + 4 * g);
    }
    const float4 g2v  = *(const float4*)(g2  + 4 * g);
    const float4 be2v = *(const float4*)(be2 + 4 * g);
    const float4 b2v  = *(const float4*)(b2  + 4 * g);

    // Rs[w][kb][q][8]: value h=kb*8+o for point q. Reads are lane-contiguous.
    __shared__ __align__(16) unsigned short Rs[4][8][16][8];
    __shared__ float wsum[4][16];

    f32x4 acc = {0.f, 0.f, 0.f, 0.f};

    const int nch = (n + CHUNK - 1) / CHUNK;
    for (int j = bx; j < nch; j += GX) {
        const int cbase = j * CHUNK + w * 64;

        // ---- batch fetch: 4 groups of 16 points -> registers ----
        bf16x8 hb[4];
        #pragma unroll
        for (int it = 0; it < 4; ++it) {
            const int gb = cbase + it * 16;
            bf16x8 hv;
            #pragma unroll
            for (int e = 0; e < 8; ++e) hv[e] = 0;
            if (gb < n) {                         // wave-uniform
                const int idx = gb + q;
                const bool v = idx < n;
                if (g < 2) {
                    int d = 0;
                    if (v) d = cd[bD + idx];
                    hv = *(const bf16x8*)(febf + (size_t)d * 16 + 8 * g);
                } else if (g == 2) {
                    float xv = 0.f;
                    if (v) { const int d = cd[bD + idx]; xv = x[bD + d]; }
                    hv[0] = (short)f2bf(xv);
                    hv[1] = (short)0x3F80;        // 1.0 -> bias column k=17
                }
            }
            hb[it] = hv;
        }

        // ---- compute 4 groups ----
        #pragma unroll
        for (int it = 0; it < 4; ++it) {
            const int gb = cbase + it * 16;
            if (gb >= n) continue;                // wave-uniform
            const f32x4 z = {0.f, 0.f, 0.f, 0.f};
            f32x4 t1a[4];
            #pragma unroll
            for (int m = 0; m < 4; ++m)
                t1a[m] = __builtin_amdgcn_mfma_f32_16x16x32_bf16(w1f[m], hb[it], z, 0, 0, 0);

            // LN over H=64 (lane holds 16 values of point q; reduce across g)
            float s0 = 0.f, s1 = 0.f, q0 = 0.f, q1 = 0.f;
            #pragma unroll
            for (int m = 0; m < 4; ++m) {
                s0 += t1a[m][0] + t1a[m][1];
                s1 += t1a[m][2] + t1a[m][3];
                q0 = fmaf(t1a[m][0], t1a[m][0], fmaf(t1a[m][1], t1a[m][1], q0));
                q1 = fmaf(t1a[m][2], t1a[m][2], fmaf(t1a[m][3], t1a[m][3], q1));
            }
            float s = s0 + s1, sq = q0 + q1;
            s  += __shfl_xor(s, 16);  sq += __shfl_xor(sq, 16);
            s  += __shfl_xor(s, 32);  sq += __shfl_xor(sq, 32);
            const float mean1 = s * (1.f / H);
            const float var1  = fmaxf(sq * (1.f / H) - mean1 * mean1, 0.f);
            const float rstd1 = rsqrtf(var1 + EPSF);

            // normalize+affine+relu -> bf16 -> Rs (h=16m+4g+r -> kb=2m+(g>>1), o=4(g&1)+r)
            #pragma unroll
            for (int m = 0; m < 4; ++m) {
                const float v0 = fmaxf(fmaf((t1a[m][0] - mean1) * rstd1, g1v[m].x, be1v[m].x), 0.f);
                const float v1 = fmaxf(fmaf((t1a[m][1] - mean1) * rstd1, g1v[m].y, be1v[m].y), 0.f);
                const float v2 = fmaxf(fmaf((t1a[m][2] - mean1) * rstd1, g1v[m].z, be1v[m].z), 0.f);
                const float v3 = fmaxf(fmaf((t1a[m][3] - mean1) * rstd1, g1v[m].w, be1v[m].w), 0.f);
                uint2 pk = make_uint2(packbf(v0, v1), packbf(v2, v3));
                *(uint2*)&Rs[w][2 * m + (g >> 1)][q][4 * (g & 1)] = pk;
            }

            const bf16x8 rb0 = *(const bf16x8*)&Rs[w][g][q][0];
            const bf16x8 rb1 = *(const bf16x8*)&Rs[w][4 + g][q][0];
            f32x4 a2 = __builtin_amdgcn_mfma_f32_16x16x32_bf16(w2f[0], rb0, z, 0, 0, 0);
            a2 = __builtin_amdgcn_mfma_f32_16x16x32_bf16(w2f[1], rb1, a2, 0, 0, 0);
            a2[0] += b2v.x; a2[1] += b2v.y; a2[2] += b2v.z; a2[3] += b2v.w;

            // LN over C=16
            float s2 = (a2[0] + a2[1]) + (a2[2] + a2[3]);
            float q2 = fmaf(a2[0], a2[0], fmaf(a2[1], a2[1],
                       fmaf(a2[2], a2[2], a2[3] * a2[3])));
            s2 += __shfl_xor(s2, 16);  q2 += __shfl_xor(q2, 16);
            s2 += __shfl_xor(s2, 32);  q2 += __shfl_xor(q2, 32);
            const float mean2 = s2 * (1.f / C);
            const float var2  = fmaxf(q2 * (1.f / C) - mean2 * mean2, 0.f);
            const float rstd2 = rsqrtf(var2 + EPSF);
            const float vm = (gb + q < n) ? 1.f : 0.f;
            acc[0] += fmaxf(fmaf((a2[0] - mean2) * rstd2, g2v.x, be2v.x), 0.f) * vm;
            acc[1] += fmaxf(fmaf((a2[1] - mean2) * rstd2, g2v.y, be2v.y), 0.f) * vm;
            acc[2] += fmaxf(fmaf((a2[2] - mean2) * rstd2, g2v.z, be2v.z), 0.f) * vm;
            acc[3] += fmaxf(fmaf((a2[3] - mean2) * rstd2, g2v.w, be2v.w), 0.f) * vm;
        }
    }

    // pool over the 16 point-columns
    #pragma unroll
    for (int off = 1; off < 16; off <<= 1) {
        #pragma unroll
        for (int r = 0; r < 4; ++r) acc[r] += __shfl_xor(acc[r], off);
    }
    if (q == 0)
        *(float4*)&wsum[w][4 * g] = make_float4(acc[0], acc[1], acc[2], acc[3]);
    __syncthreads();
    if (tid < C)
        part[((size_t)b * GX + bx) * C + tid] =
            wsum[0][tid] + wsum[1][tid] + wsum[2][tid] + wsum[3][tid];
}

// ---------- K4: encoder MLP per batch ----------
__global__ __launch_bounds__(EH) void k_enc(
    const float* __restrict__ part, const int* __restrict__ cnt,
    const float* __restrict__ We1, const float* __restrict__ bb1,
    const float* __restrict__ gg1, const float* __restrict__ bbe1,
    const float* __restrict__ We2, const float* __restrict__ bb2,
    const float* __restrict__ gg2, const float* __restrict__ bbe2,
    float* __restrict__ out)
{
    const int b = blockIdx.x;
    const int t = threadIdx.x;
    __shared__ float cc[C];
    __shared__ float stats[2];
    __shared__ float buf[EH];
    __shared__ float buf2[2 * L];

    const int n = cnt[b];
    if (t < C) {
        float s = 0.f;
        #pragma unroll
        for (int j = 0; j < GX; ++j)
            s += part[((size_t)b * GX + j) * C + t];
        cc[t] = s;
    }
    __syncthreads();
    const float inv = 1.f / fmaxf((float)n, 1.f);

    float v1 = bb1[t];
    #pragma unroll
    for (int c = 0; c < C; ++c)
        v1 = fmaf(cc[c] * inv, We1[c * EH + t], v1);
    buf[t] = v1;
    __syncthreads();
    if (t == 0) {
        float s = 0.f, ss = 0.f;
        for (int j2 = 0; j2 < EH; ++j2) { s += buf[j2]; ss = fmaf(buf[j2], buf[j2], ss); }
        float mn = s * (1.f / EH);
        float vr = fmaxf(ss * (1.f / EH) - mn * mn, 0.f);
        stats[0] = mn; stats[1] = rsqrtf(vr + EPSF);
    }
    __syncthreads();
    float e1 = fmaxf(fmaf((v1 - stats[0]) * stats[1], gg1[t], bbe1[t]), 0.f);
    __syncthreads();
    buf[t] = e1;
    __syncthreads();

    float v2 = 0.f;
    if (t < 2 * L) {
        v2 = bb2[t];
        #pragma unroll
        for (int h = 0; h < EH; ++h)
            v2 = fmaf(buf[h], We2[h * (2 * L) + t], v2);
        buf2[t] = v2;
    }
    __syncthreads();
    if (t == 0) {
        float s = 0.f, ss = 0.f;
        for (int j2 = 0; j2 < 2 * L; ++j2) { s += buf2[j2]; ss = fmaf(buf2[j2], buf2[j2], ss); }
        float mn = s * (1.f / (2 * L));
        float vr = fmaxf(ss * (1.f / (2 * L)) - mn * mn, 0.f);
        stats[0] = mn; stats[1] = rsqrtf(vr + EPSF);
    }
    __syncthreads();
    if (t < 2 * L) {
        float e2 = fmaxf(fmaf((v2 - stats[0]) * stats[1], gg2[t], bbe2[t]), 0.f);
        if (t < L) out[(size_t)b * L + t]                       = e2;  // mu
        else       out[(size_t)B * L + (size_t)b * L + (t - L)] = e2;  // logvar
    }
}

extern "C" void kernel_launch(void* const* d_in, const int* in_sizes, int n_in,
                              void* d_out, int out_size, void* d_ws, size_t ws_size,
                              hipStream_t stream) {
    const float* x    = (const float*)d_in[0];
    const int*   mask = (const int*)d_in[1];
    const float* fe   = (const float*)d_in[2];
    const float* W1   = (const float*)d_in[3];
    const float* b1   = (const float*)d_in[4];
    const float* g1   = (const float*)d_in[5];
    const float* be1  = (const float*)d_in[6];
    const float* W2   = (const float*)d_in[7];
    const float* b2   = (const float*)d_in[8];
    const float* g2   = (const float*)d_in[9];
    const float* be2  = (const float*)d_in[10];
    const float* We1  = (const float*)d_in[11];
    const float* bb1  = (const float*)d_in[12];
    const float* gg1  = (const float*)d_in[13];
    const float* bbe1 = (const float*)d_in[14];
    const float* We2  = (const float*)d_in[15];
    const float* bb2  = (const float*)d_in[16];
    const float* gg2  = (const float*)d_in[17];
    const float* bbe2 = (const float*)d_in[18];
    float* out = (float*)d_out;

    char* wp = (char*)d_ws;
    float* part     = (float*)wp;               wp += (size_t)B * GX * C * 4;   // 48 KB
    int*   cnt      = (int*)wp;                 wp += (size_t)B * 4;
    int*   chunkpop = (int*)wp;                 wp += (size_t)B * NCHUNK * 4;   // 20 KB
    unsigned short* W1T  = (unsigned short*)wp; wp += (size_t)H * 32 * 2;       // 4 KB
    unsigned short* W2T  = (unsigned short*)wp; wp += (size_t)C * H * 2;        // 2 KB
    unsigned short* febf = (unsigned short*)wp; wp += (size_t)D * C * 2;        // 640 KB
    unsigned short* cd   = (unsigned short*)wp;                                  // 2.56 MB

    hipLaunchKernelGGL(k_count_prep, dim3(NCHUNK + 1, B), dim3(256), 0, stream,
                       mask, fe, W1, b1, W2, chunkpop, febf, W1T, W2T);
    hipLaunchKernelGGL(k_scatter, dim3(NCHUNK, B), dim3(256), 0, stream,
                       mask, chunkpop, cd, cnt);
    hipLaunchKernelGGL(k_rows, dim3(GX, B), dim3(256), 0, stream,
                       x, cd, cnt, febf, W1T, W2T, g1, be1, g2, be2, b2, part);
    hipLaunchKernelGGL(k_enc, dim3(B), dim3(EH), 0, stream,
                       part, cnt, We1, bb1, gg1, bbe1, We2, bb2, gg2, bbe2, out);
}